// Round 1
// baseline (801.526 us; speedup 1.0000x reference)
//
#include <hip/hip_runtime.h>

#define T_STEPS 200
#define OUTD 28

__device__ __forceinline__ float fast_rcp(float x) { return __builtin_amdgcn_rcpf(x); }
__device__ __forceinline__ float fast_exp2(float x) { return __builtin_amdgcn_exp2f(x); }
// sigmoid(x) = 1/(1+exp(-x)) = rcp(1 + 2^(-x*log2e))
__device__ __forceinline__ float sigm(float x) {
    return fast_rcp(1.0f + fast_exp2(-1.4426950408889634f * x));
}
// tanh(x) = 1 - 2/(1+exp(2x)) = 1 - 2*rcp(1 + 2^(x*2*log2e))
__device__ __forceinline__ float tanh_fast(float x) {
    return 1.0f - 2.0f * fast_rcp(1.0f + fast_exp2(2.8853900817779268f * x));
}

// One thread = one batch element. Both LSTM layers + the final linear are fused;
// the linear is accumulated online per timestep so h2 is never materialized.
// block=64, __launch_bounds__(64,1): 1 wave/SIMD occupancy cap is structural
// (only 512 waves exist), so we can afford ~350 unified VGPR/AGPR regs of
// per-thread weights without hurting occupancy.
__global__ __launch_bounds__(64, 1)
void lstm2_linear_kernel(const float* __restrict__ x,
                         const float* __restrict__ Wih0, const float* __restrict__ Whh0,
                         const float* __restrict__ bih0, const float* __restrict__ bhh0,
                         const float* __restrict__ Wih1, const float* __restrict__ Whh1,
                         const float* __restrict__ bih1, const float* __restrict__ bhh1,
                         const float* __restrict__ Wout, const float* __restrict__ bout,
                         float* __restrict__ out, int batch)
{
    const int b = blockIdx.x * 64 + threadIdx.x;
    if (b >= batch) return;

    // Preload all LSTM weights into registers. All lanes read the same
    // addresses -> L1 broadcast, one-time cost.
    float w0[16][8];   // [j][0..3] = Wih0 row j, [j][4..7] = Whh0 row j
    float w1[16][8];
    float bias0[16], bias1[16];
#pragma unroll
    for (int j = 0; j < 16; ++j) {
        float4 a = ((const float4*)Wih0)[j];
        float4 c = ((const float4*)Whh0)[j];
        w0[j][0] = a.x; w0[j][1] = a.y; w0[j][2] = a.z; w0[j][3] = a.w;
        w0[j][4] = c.x; w0[j][5] = c.y; w0[j][6] = c.z; w0[j][7] = c.w;
        float4 d = ((const float4*)Wih1)[j];
        float4 e = ((const float4*)Whh1)[j];
        w1[j][0] = d.x; w1[j][1] = d.y; w1[j][2] = d.z; w1[j][3] = d.w;
        w1[j][4] = e.x; w1[j][5] = e.y; w1[j][6] = e.z; w1[j][7] = e.w;
        bias0[j] = bih0[j] + bhh0[j];
        bias1[j] = bih1[j] + bhh1[j];
    }

    float h1[4] = {0,0,0,0}, c1[4] = {0,0,0,0};
    float h2[4] = {0,0,0,0}, c2[4] = {0,0,0,0};
    float acc[OUTD];
#pragma unroll
    for (int j = 0; j < OUTD; ++j) acc[j] = bout[j];

    const float4* xp = (const float4*)(x + (size_t)b * (T_STEPS * 4));

    for (int t = 0; t < T_STEPS; ++t) {
        float4 xv = xp[t];   // x[b, t, 0..3]

        // ---- layer 1 gates: g = Wih0 @ x_t + Whh0 @ h1 + bias ----
        float g[16];
#pragma unroll
        for (int j = 0; j < 16; ++j) {
            float s = bias0[j];
            s += w0[j][0] * xv.x;  s += w0[j][1] * xv.y;
            s += w0[j][2] * xv.z;  s += w0[j][3] * xv.w;
            s += w0[j][4] * h1[0]; s += w0[j][5] * h1[1];
            s += w0[j][6] * h1[2]; s += w0[j][7] * h1[3];
            g[j] = s;
        }
#pragma unroll
        for (int k = 0; k < 4; ++k) {
            float ig = sigm(g[k]);
            float fg = sigm(g[4 + k]);
            float gg = tanh_fast(g[8 + k]);
            float og = sigm(g[12 + k]);
            float c = fg * c1[k] + ig * gg;
            c1[k] = c;
            h1[k] = og * tanh_fast(c);
        }

        // ---- layer 2 gates: g = Wih1 @ h1 + Whh1 @ h2 + bias ----
#pragma unroll
        for (int j = 0; j < 16; ++j) {
            float s = bias1[j];
            s += w1[j][0] * h1[0]; s += w1[j][1] * h1[1];
            s += w1[j][2] * h1[2]; s += w1[j][3] * h1[3];
            s += w1[j][4] * h2[0]; s += w1[j][5] * h2[1];
            s += w1[j][6] * h2[2]; s += w1[j][7] * h2[3];
            g[j] = s;
        }
#pragma unroll
        for (int k = 0; k < 4; ++k) {
            float ig = sigm(g[k]);
            float fg = sigm(g[4 + k]);
            float gg = tanh_fast(g[8 + k]);
            float og = sigm(g[12 + k]);
            float c = fg * c2[k] + ig * gg;
            c2[k] = c;
            h2[k] = og * tanh_fast(c);
        }

        // ---- fused linear: acc[j] += h2 . Wout[j, 4t : 4t+4] ----
        // Indices are wave-uniform -> scalar loads from K$/L2.
        const float* wr = Wout + t * 4;
#pragma unroll
        for (int j = 0; j < OUTD; ++j) {
            const float* w = wr + j * 800;
            acc[j] += w[0] * h2[0] + w[1] * h2[1] + w[2] * h2[2] + w[3] * h2[3];
        }
    }

    float* op = out + (size_t)b * OUTD;
#pragma unroll
    for (int j = 0; j < OUTD; ++j) op[j] = acc[j];
}

extern "C" void kernel_launch(void* const* d_in, const int* in_sizes, int n_in,
                              void* d_out, int out_size, void* d_ws, size_t ws_size,
                              hipStream_t stream) {
    const float* x    = (const float*)d_in[0];
    const float* Wih0 = (const float*)d_in[1];
    const float* Whh0 = (const float*)d_in[2];
    const float* bih0 = (const float*)d_in[3];
    const float* bhh0 = (const float*)d_in[4];
    const float* Wih1 = (const float*)d_in[5];
    const float* Whh1 = (const float*)d_in[6];
    const float* bih1 = (const float*)d_in[7];
    const float* bhh1 = (const float*)d_in[8];
    const float* Wout = (const float*)d_in[9];
    const float* bout = (const float*)d_in[10];
    float* out = (float*)d_out;

    const int batch = in_sizes[0] / (T_STEPS * 4);   // 32768
    const int block = 64;
    const int grid = (batch + block - 1) / block;    // 512
    lstm2_linear_kernel<<<grid, block, 0, stream>>>(
        x, Wih0, Whh0, bih0, bhh0, Wih1, Whh1, bih1, bhh1, Wout, bout, out, batch);
}

// Round 2
// 494.229 us; speedup vs baseline: 1.6218x; 1.6218x over previous
//
#include <hip/hip_runtime.h>

#define T_STEPS 200
#define OUTD 28

__device__ __forceinline__ float sigm(float x) {
    return __builtin_amdgcn_rcpf(1.0f + __builtin_amdgcn_exp2f(-1.4426950408889634f * x));
}
__device__ __forceinline__ float tanh_fast(float x) {
    return 1.0f - 2.0f * __builtin_amdgcn_rcpf(1.0f + __builtin_amdgcn_exp2f(2.8853900817779268f * x));
}

// Broadcast lane SRC of each quad to all 4 lanes of the quad (one VALU op).
template<int SRC>
__device__ __forceinline__ float qb(float v) {
    return __int_as_float(__builtin_amdgcn_update_dpp(
        0, __float_as_int(v), SRC * 0x55, 0xF, 0xF, true));
}

// 4 lanes cooperate on one batch element. Lane k (=tid&3) owns hidden unit k:
// it computes gate rows {k, 4+k, 8+k, 12+k} of both layers (weights fully
// register-resident: 64 floats + 8 biases per lane), keeps c1[k]/c2[k], and
// broadcasts its h via DPP quad_perm. The final linear is split 7 outputs per
// lane (28 = 4*7), accumulated online so h2 is never materialized.
// 32768 elements * 4 lanes = 131072 threads = 2048 waves = 2 waves/SIMD.
__global__ __launch_bounds__(256, 2)
void lstm2_fused(const float* __restrict__ x,
                 const float* __restrict__ Wih0, const float* __restrict__ Whh0,
                 const float* __restrict__ bih0, const float* __restrict__ bhh0,
                 const float* __restrict__ Wih1, const float* __restrict__ Whh1,
                 const float* __restrict__ bih1, const float* __restrict__ bhh1,
                 const float* __restrict__ Wout, const float* __restrict__ bout,
                 float* __restrict__ out, int batch)
{
    const int tid = blockIdx.x * 256 + threadIdx.x;
    const int b = tid >> 2;       // batch element
    const int k = tid & 3;        // hidden-unit index owned by this lane
    if (b >= batch) return;       // never taken (32768*4 divisible by 256)

    // ---- preamble: per-lane weights into registers ----
    float4 wi0[4], wh0[4], wi1[4], wh1[4];
    float b0[4], b1[4];
#pragma unroll
    for (int gi = 0; gi < 4; ++gi) {
        const int row = gi * 4 + k;              // rows k,4+k,8+k,12+k
        wi0[gi] = ((const float4*)Wih0)[row];
        wh0[gi] = ((const float4*)Whh0)[row];
        wi1[gi] = ((const float4*)Wih1)[row];
        wh1[gi] = ((const float4*)Whh1)[row];
        b0[gi] = bih0[row] + bhh0[row];
        b1[gi] = bih1[row] + bhh1[row];
    }

    float acc[7];
#pragma unroll
    for (int jj = 0; jj < 7; ++jj) acc[jj] = bout[k * 7 + jj];

    float h1[4] = {0,0,0,0}, h2[4] = {0,0,0,0};
    float c1 = 0.0f, c2 = 0.0f;

    const float4* xp = (const float4*)(x + (size_t)b * (T_STEPS * 4));
    const float* wb = Wout + (size_t)(k * 7) * 800;   // this lane's 7 Wout rows

    float4 xv = xp[0];

    for (int t = 0; t < T_STEPS; ++t) {
        // ---- issue this step's Wout loads + next x early (hidden behind
        //      the ~300 VALU cycles of the two LSTM layers) ----
        float4 wo[7];
#pragma unroll
        for (int jj = 0; jj < 7; ++jj)
            wo[jj] = *(const float4*)(wb + jj * 800 + 4 * t);
        float4 xnext = xp[t < T_STEPS - 1 ? t + 1 : t];

        // ---- layer 1: 4 gate rows for unit k ----
        float g[4];
#pragma unroll
        for (int gi = 0; gi < 4; ++gi) {
            g[gi] = b0[gi]
                  + wi0[gi].x * xv.x + wi0[gi].y * xv.y
                  + wi0[gi].z * xv.z + wi0[gi].w * xv.w
                  + wh0[gi].x * h1[0] + wh0[gi].y * h1[1]
                  + wh0[gi].z * h1[2] + wh0[gi].w * h1[3];
        }
        {
            float ig = sigm(g[0]), fg = sigm(g[1]);
            float gg = tanh_fast(g[2]), og = sigm(g[3]);
            c1 = fg * c1 + ig * gg;
            float ho = og * tanh_fast(c1);
            h1[0] = qb<0>(ho); h1[1] = qb<1>(ho);
            h1[2] = qb<2>(ho); h1[3] = qb<3>(ho);
        }

        // ---- layer 2 ----
#pragma unroll
        for (int gi = 0; gi < 4; ++gi) {
            g[gi] = b1[gi]
                  + wi1[gi].x * h1[0] + wi1[gi].y * h1[1]
                  + wi1[gi].z * h1[2] + wi1[gi].w * h1[3]
                  + wh1[gi].x * h2[0] + wh1[gi].y * h2[1]
                  + wh1[gi].z * h2[2] + wh1[gi].w * h2[3];
        }
        {
            float ig = sigm(g[0]), fg = sigm(g[1]);
            float gg = tanh_fast(g[2]), og = sigm(g[3]);
            c2 = fg * c2 + ig * gg;
            float ho = og * tanh_fast(c2);
            h2[0] = qb<0>(ho); h2[1] = qb<1>(ho);
            h2[2] = qb<2>(ho); h2[3] = qb<3>(ho);
        }

        // ---- fused linear: this lane's 7 outputs ----
#pragma unroll
        for (int jj = 0; jj < 7; ++jj) {
            acc[jj] += wo[jj].x * h2[0] + wo[jj].y * h2[1]
                     + wo[jj].z * h2[2] + wo[jj].w * h2[3];
        }

        xv = xnext;
    }

    float* op = out + (size_t)b * OUTD + k * 7;
#pragma unroll
    for (int jj = 0; jj < 7; ++jj) op[jj] = acc[jj];
}

extern "C" void kernel_launch(void* const* d_in, const int* in_sizes, int n_in,
                              void* d_out, int out_size, void* d_ws, size_t ws_size,
                              hipStream_t stream) {
    const float* x    = (const float*)d_in[0];
    const float* Wih0 = (const float*)d_in[1];
    const float* Whh0 = (const float*)d_in[2];
    const float* bih0 = (const float*)d_in[3];
    const float* bhh0 = (const float*)d_in[4];
    const float* Wih1 = (const float*)d_in[5];
    const float* Whh1 = (const float*)d_in[6];
    const float* bih1 = (const float*)d_in[7];
    const float* bhh1 = (const float*)d_in[8];
    const float* Wout = (const float*)d_in[9];
    const float* bout = (const float*)d_in[10];
    float* out = (float*)d_out;

    const int batch = in_sizes[0] / (T_STEPS * 4);   // 32768
    const int threads = batch * 4;                   // 131072
    const int block = 256;
    const int grid = (threads + block - 1) / block;  // 512
    lstm2_fused<<<grid, block, 0, stream>>>(
        x, Wih0, Whh0, bih0, bhh0, Wih1, Whh1, bih1, bhh1, Wout, bout, out, batch);
}

// Round 3
// 370.772 us; speedup vs baseline: 2.1618x; 1.3330x over previous
//
#include <hip/hip_runtime.h>

#define T_STEPS 200
#define OUTD 28

__device__ __forceinline__ float sigm(float x) {
    return __builtin_amdgcn_rcpf(1.0f + __builtin_amdgcn_exp2f(-1.4426950408889634f * x));
}
__device__ __forceinline__ float tanh_fast(float x) {
    return 1.0f - 2.0f * __builtin_amdgcn_rcpf(1.0f + __builtin_amdgcn_exp2f(2.8853900817779268f * x));
}

// Broadcast lane SRC of each quad to all 4 lanes of the quad (one VALU op).
template<int SRC>
__device__ __forceinline__ float qb(float v) {
    return __int_as_float(__builtin_amdgcn_update_dpp(
        0, __float_as_int(v), SRC * 0x55, 0xF, 0xF, true));
}

// Pin a value into a VGPR: asm output is opaque -> cannot be rematerialized
// (prevents the allocator from re-loading loop-invariant weights every step).
#define PINF(v) asm volatile("" : "+v"(v))
#define PIN4(f) do { PINF((f).x); PINF((f).y); PINF((f).z); PINF((f).w); } while (0)

// Prep: Wt[t][j][c] = Wout[j][4t+c]  (so per-step Wout values are contiguous:
// one uniform base bump of 448B/step + constant lane offsets).
__global__ void transpose_wout(const float* __restrict__ Wout, float* __restrict__ Wt) {
    int idx = blockIdx.x * 256 + threadIdx.x;     // 200*28*4 = 22400
    if (idx < T_STEPS * OUTD * 4) {
        int t = idx / (OUTD * 4);
        int r = idx - t * (OUTD * 4);
        int j = r >> 2, c = r & 3;
        Wt[idx] = Wout[j * 800 + 4 * t + c];
    }
}

// 4 lanes per batch element; lane k owns hidden unit k (gate rows k,4+k,8+k,12+k
// of both layers, weights pinned register-resident), h broadcast via DPP
// quad_perm, final linear split 7 outputs/lane and accumulated online.
// 32768 elem * 4 lanes = 2048 waves = 2 waves/SIMD on all 1024 SIMDs.
__global__ __launch_bounds__(256, 2)
void lstm2_fused(const float* __restrict__ x,
                 const float* __restrict__ Wih0, const float* __restrict__ Whh0,
                 const float* __restrict__ bih0, const float* __restrict__ bhh0,
                 const float* __restrict__ Wih1, const float* __restrict__ Whh1,
                 const float* __restrict__ bih1, const float* __restrict__ bhh1,
                 const float* __restrict__ Wt,   const float* __restrict__ bout,
                 float* __restrict__ out, int batch)
{
    const int tid = blockIdx.x * 256 + threadIdx.x;
    const int b = tid >> 2;       // batch element
    const int k = tid & 3;        // hidden unit owned by this lane
    if (b >= batch) return;       // never taken

    // ---- preamble: per-lane weights into registers, then pin them ----
    float4 wi0[4], wh0[4], wi1[4], wh1[4];
    float b0[4], b1[4];
#pragma unroll
    for (int gi = 0; gi < 4; ++gi) {
        const int row = gi * 4 + k;              // rows k,4+k,8+k,12+k
        wi0[gi] = ((const float4*)Wih0)[row];
        wh0[gi] = ((const float4*)Whh0)[row];
        wi1[gi] = ((const float4*)Wih1)[row];
        wh1[gi] = ((const float4*)Whh1)[row];
        b0[gi] = bih0[row] + bhh0[row];
        b1[gi] = bih1[row] + bhh1[row];
    }
#pragma unroll
    for (int gi = 0; gi < 4; ++gi) {
        PIN4(wi0[gi]); PIN4(wh0[gi]); PIN4(wi1[gi]); PIN4(wh1[gi]);
        PINF(b0[gi]);  PINF(b1[gi]);
    }

    float acc[7];
#pragma unroll
    for (int jj = 0; jj < 7; ++jj) acc[jj] = bout[k * 7 + jj];

    float h1[4] = {0,0,0,0}, h2[4] = {0,0,0,0};
    float c1 = 0.0f, c2 = 0.0f;

    // Uniform bases (SALU-advanced) + constant per-lane byte offsets.
    const char* xp  = (const char*)x;                 // + t*16 each step
    const unsigned x_off = (unsigned)b * 3200u;       // b * 200*4*4B
    const char* wtp = (const char*)Wt;                // + 448 each step
    const unsigned w_off = (unsigned)k * 112u;        // k*7 rows * 16B

    float4 xv = *(const float4*)(xp + x_off);

    for (int t = 0; t < T_STEPS; ++t) {
        // ---- this step's Wout column (7x float4) + next x, issued early ----
        float4 wo[7];
#pragma unroll
        for (int jj = 0; jj < 7; ++jj)
            wo[jj] = *(const float4*)(wtp + w_off + jj * 16);
        wtp += OUTD * 16;                              // uniform s_add

        int tn = t + 1; if (tn >= T_STEPS) tn = T_STEPS - 1;   // uniform
        float4 xnext = *(const float4*)(xp + x_off + (size_t)tn * 16);

        // ---- layer 1: 4 gate rows for unit k ----
        float g[4];
#pragma unroll
        for (int gi = 0; gi < 4; ++gi) {
            g[gi] = b0[gi]
                  + wi0[gi].x * xv.x + wi0[gi].y * xv.y
                  + wi0[gi].z * xv.z + wi0[gi].w * xv.w
                  + wh0[gi].x * h1[0] + wh0[gi].y * h1[1]
                  + wh0[gi].z * h1[2] + wh0[gi].w * h1[3];
        }
        {
            float ig = sigm(g[0]), fg = sigm(g[1]);
            float gg = tanh_fast(g[2]), og = sigm(g[3]);
            c1 = fg * c1 + ig * gg;
            float ho = og * tanh_fast(c1);
            h1[0] = qb<0>(ho); h1[1] = qb<1>(ho);
            h1[2] = qb<2>(ho); h1[3] = qb<3>(ho);
        }

        // ---- layer 2 ----
#pragma unroll
        for (int gi = 0; gi < 4; ++gi) {
            g[gi] = b1[gi]
                  + wi1[gi].x * h1[0] + wi1[gi].y * h1[1]
                  + wi1[gi].z * h1[2] + wi1[gi].w * h1[3]
                  + wh1[gi].x * h2[0] + wh1[gi].y * h2[1]
                  + wh1[gi].z * h2[2] + wh1[gi].w * h2[3];
        }
        {
            float ig = sigm(g[0]), fg = sigm(g[1]);
            float gg = tanh_fast(g[2]), og = sigm(g[3]);
            c2 = fg * c2 + ig * gg;
            float ho = og * tanh_fast(c2);
            h2[0] = qb<0>(ho); h2[1] = qb<1>(ho);
            h2[2] = qb<2>(ho); h2[3] = qb<3>(ho);
        }

        // ---- fused linear: this lane's 7 outputs ----
#pragma unroll
        for (int jj = 0; jj < 7; ++jj) {
            acc[jj] += wo[jj].x * h2[0] + wo[jj].y * h2[1]
                     + wo[jj].z * h2[2] + wo[jj].w * h2[3];
        }

        xv = xnext;
    }

    float* op = out + (size_t)b * OUTD + k * 7;
#pragma unroll
    for (int jj = 0; jj < 7; ++jj) op[jj] = acc[jj];
}

extern "C" void kernel_launch(void* const* d_in, const int* in_sizes, int n_in,
                              void* d_out, int out_size, void* d_ws, size_t ws_size,
                              hipStream_t stream) {
    const float* x    = (const float*)d_in[0];
    const float* Wih0 = (const float*)d_in[1];
    const float* Whh0 = (const float*)d_in[2];
    const float* bih0 = (const float*)d_in[3];
    const float* bhh0 = (const float*)d_in[4];
    const float* Wih1 = (const float*)d_in[5];
    const float* Whh1 = (const float*)d_in[6];
    const float* bih1 = (const float*)d_in[7];
    const float* bhh1 = (const float*)d_in[8];
    const float* Wout = (const float*)d_in[9];
    const float* bout = (const float*)d_in[10];
    float* out = (float*)d_out;
    float* Wt  = (float*)d_ws;      // 200*28*4 floats = 89.6 KB

    transpose_wout<<<(T_STEPS * OUTD * 4 + 255) / 256, 256, 0, stream>>>(Wout, Wt);

    const int batch = in_sizes[0] / (T_STEPS * 4);   // 32768
    const int threads = batch * 4;                   // 131072
    const int grid = threads / 256;                  // 512
    lstm2_fused<<<grid, 256, 0, stream>>>(
        x, Wih0, Whh0, bih0, bhh0, Wih1, Whh1, bih1, bhh1, Wt, bout, out, batch);
}

// Round 4
// 299.840 us; speedup vs baseline: 2.6732x; 1.2366x over previous
//
#include <hip/hip_runtime.h>

#define T_STEPS 200
#define OUTD 28

typedef float f2 __attribute__((ext_vector_type(2)));

__device__ __forceinline__ float sigm(float x) {
    return __builtin_amdgcn_rcpf(1.0f + __builtin_amdgcn_exp2f(-1.4426950408889634f * x));
}
__device__ __forceinline__ float tanh_fast(float x) {
    return 1.0f - 2.0f * __builtin_amdgcn_rcpf(1.0f + __builtin_amdgcn_exp2f(2.8853900817779268f * x));
}

// Broadcast lane SRC of each quad to all 4 lanes of the quad (one VALU op).
template<int SRC>
__device__ __forceinline__ float qb(float v) {
    return __int_as_float(__builtin_amdgcn_update_dpp(
        0, __float_as_int(v), SRC * 0x55, 0xF, 0xF, true));
}

// Prep: Wt[t][j][c] = Wout[j][4t+c]  (per-step Wout column contiguous:
// uniform base bump 448B/step + constant lane offset).
__global__ void transpose_wout(const float* __restrict__ Wout, float* __restrict__ Wt) {
    int idx = blockIdx.x * 256 + threadIdx.x;     // 200*28*4 = 22400
    if (idx < T_STEPS * OUTD * 4) {
        int t = idx / (OUTD * 4);
        int r = idx - t * (OUTD * 4);
        int j = r >> 2, c = r & 3;
        Wt[idx] = Wout[j * 800 + 4 * t + c];
    }
}

// 4 lanes per batch element; lane k owns hidden unit k (gate rows
// k,4+k,8+k,12+k of both layers). Weights register-resident as float2 pairs
// (v_pk_fma_f32); h broadcast via DPP quad_perm; final linear split
// 7 outputs/lane with float2 accumulators folded after the loop.
// amdgpu_waves_per_eu(2,2): grid provides exactly 2 waves/SIMD, so pin the
// allocator to the 256-reg budget — without this it targets high occupancy
// and parks the weight set in AGPRs, paying v_accvgpr_read on every use
// (R3: VGPR_Count=64, ~2.7x instruction bloat).
__global__ __launch_bounds__(256)
__attribute__((amdgpu_waves_per_eu(2, 2)))
void lstm2_fused(const float* __restrict__ x,
                 const float* __restrict__ Wih0, const float* __restrict__ Whh0,
                 const float* __restrict__ bih0, const float* __restrict__ bhh0,
                 const float* __restrict__ Wih1, const float* __restrict__ Whh1,
                 const float* __restrict__ bih1, const float* __restrict__ bhh1,
                 const float* __restrict__ Wt,   const float* __restrict__ bout,
                 float* __restrict__ out, int batch)
{
    const int tid = blockIdx.x * 256 + threadIdx.x;
    const int b = tid >> 2;       // batch element
    const int k = tid & 3;        // hidden unit owned by this lane
    if (b >= batch) return;       // never taken

    // ---- per-lane weights into registers (as float2 pairs) ----
    f2 wi0a[4], wi0b[4], wh0a[4], wh0b[4];
    f2 wi1a[4], wi1b[4], wh1a[4], wh1b[4];
    float b0[4], b1[4];
#pragma unroll
    for (int gi = 0; gi < 4; ++gi) {
        const int row = gi * 4 + k;              // rows k,4+k,8+k,12+k
        float4 a = ((const float4*)Wih0)[row];
        float4 c = ((const float4*)Whh0)[row];
        float4 d = ((const float4*)Wih1)[row];
        float4 e = ((const float4*)Whh1)[row];
        wi0a[gi] = f2{a.x, a.y}; wi0b[gi] = f2{a.z, a.w};
        wh0a[gi] = f2{c.x, c.y}; wh0b[gi] = f2{c.z, c.w};
        wi1a[gi] = f2{d.x, d.y}; wi1b[gi] = f2{d.z, d.w};
        wh1a[gi] = f2{e.x, e.y}; wh1b[gi] = f2{e.z, e.w};
        b0[gi] = bih0[row] + bhh0[row];
        b1[gi] = bih1[row] + bhh1[row];
    }

    f2 acc[7];
#pragma unroll
    for (int jj = 0; jj < 7; ++jj) acc[jj] = f2{bout[k * 7 + jj], 0.0f};

    f2 h1a = f2{0,0}, h1b = f2{0,0}, h2a = f2{0,0}, h2b = f2{0,0};
    float c1 = 0.0f, c2 = 0.0f;

    // Uniform bases (SALU-advanced) + constant per-lane byte offsets.
    const char* xp  = (const char*)x;                 // + t*16 each step
    const unsigned x_off = (unsigned)b * 3200u;       // b * 200*4*4B
    const char* wtp = (const char*)Wt;                // + 448 each step
    const unsigned w_off = (unsigned)k * 112u;        // k*7 rows * 16B

    float4 xv = *(const float4*)(xp + x_off);

    for (int t = 0; t < T_STEPS; ++t) {
        // ---- this step's Wout column (7x float4) + next x, issued early ----
        float4 wo[7];
#pragma unroll
        for (int jj = 0; jj < 7; ++jj)
            wo[jj] = *(const float4*)(wtp + w_off + jj * 16);
        wtp += OUTD * 16;                              // uniform s_add

        int tn = t + 1; if (tn >= T_STEPS) tn = T_STEPS - 1;   // uniform
        float4 xnext = *(const float4*)(xp + x_off + (size_t)tn * 16);

        f2 xa = f2{xv.x, xv.y}, xb = f2{xv.z, xv.w};

        // ---- layer 1: 4 gate rows for unit k (packed fp32) ----
        float g[4];
#pragma unroll
        for (int gi = 0; gi < 4; ++gi) {
            f2 s = f2{b0[gi], 0.0f};
            s += wi0a[gi] * xa;  s += wi0b[gi] * xb;
            s += wh0a[gi] * h1a; s += wh0b[gi] * h1b;
            g[gi] = s.x + s.y;
        }
        {
            float ig = sigm(g[0]), fg = sigm(g[1]);
            float gg = tanh_fast(g[2]), og = sigm(g[3]);
            c1 = fg * c1 + ig * gg;
            float ho = og * tanh_fast(c1);
            h1a = f2{qb<0>(ho), qb<1>(ho)};
            h1b = f2{qb<2>(ho), qb<3>(ho)};
        }

        // ---- layer 2 ----
#pragma unroll
        for (int gi = 0; gi < 4; ++gi) {
            f2 s = f2{b1[gi], 0.0f};
            s += wi1a[gi] * h1a; s += wi1b[gi] * h1b;
            s += wh1a[gi] * h2a; s += wh1b[gi] * h2b;
            g[gi] = s.x + s.y;
        }
        {
            float ig = sigm(g[0]), fg = sigm(g[1]);
            float gg = tanh_fast(g[2]), og = sigm(g[3]);
            c2 = fg * c2 + ig * gg;
            float ho = og * tanh_fast(c2);
            h2a = f2{qb<0>(ho), qb<1>(ho)};
            h2b = f2{qb<2>(ho), qb<3>(ho)};
        }

        // ---- fused linear: this lane's 7 outputs, packed accumulators ----
#pragma unroll
        for (int jj = 0; jj < 7; ++jj) {
            acc[jj] += f2{wo[jj].x, wo[jj].y} * h2a;
            acc[jj] += f2{wo[jj].z, wo[jj].w} * h2b;
        }

        xv = xnext;
    }

    float* op = out + (size_t)b * OUTD + k * 7;
#pragma unroll
    for (int jj = 0; jj < 7; ++jj) op[jj] = acc[jj].x + acc[jj].y;
}

extern "C" void kernel_launch(void* const* d_in, const int* in_sizes, int n_in,
                              void* d_out, int out_size, void* d_ws, size_t ws_size,
                              hipStream_t stream) {
    const float* x    = (const float*)d_in[0];
    const float* Wih0 = (const float*)d_in[1];
    const float* Whh0 = (const float*)d_in[2];
    const float* bih0 = (const float*)d_in[3];
    const float* bhh0 = (const float*)d_in[4];
    const float* Wih1 = (const float*)d_in[5];
    const float* Whh1 = (const float*)d_in[6];
    const float* bih1 = (const float*)d_in[7];
    const float* bhh1 = (const float*)d_in[8];
    const float* Wout = (const float*)d_in[9];
    const float* bout = (const float*)d_in[10];
    float* out = (float*)d_out;
    float* Wt  = (float*)d_ws;      // 200*28*4 floats = 89.6 KB

    transpose_wout<<<(T_STEPS * OUTD * 4 + 255) / 256, 256, 0, stream>>>(Wout, Wt);

    const int batch = in_sizes[0] / (T_STEPS * 4);   // 32768
    const int threads = batch * 4;                   // 131072
    const int grid = threads / 256;                  // 512
    lstm2_fused<<<grid, 256, 0, stream>>>(
        x, Wih0, Whh0, bih0, bhh0, Wih1, Whh1, bih1, bhh1, Wt, bout, out, batch);
}

// Round 5
// 268.756 us; speedup vs baseline: 2.9824x; 1.1157x over previous
//
#include <hip/hip_runtime.h>

#define T_STEPS 200
#define OUTD 28

typedef float f2 __attribute__((ext_vector_type(2)));

__device__ __forceinline__ float sigm(float x) {
    return __builtin_amdgcn_rcpf(1.0f + __builtin_amdgcn_exp2f(-1.4426950408889634f * x));
}
__device__ __forceinline__ float tanh_fast(float x) {
    return 1.0f - 2.0f * __builtin_amdgcn_rcpf(1.0f + __builtin_amdgcn_exp2f(2.8853900817779268f * x));
}

// Broadcast lane SRC of each quad to all 4 lanes of the quad (one VALU op).
template<int SRC>
__device__ __forceinline__ float qb(float v) {
    return __int_as_float(__builtin_amdgcn_update_dpp(
        0, __float_as_int(v), SRC * 0x55, 0xF, 0xF, true));
}

// Pin an f2 (VGPR pair) so the allocator cannot rematerialize/reload it.
#define PIN2(v) asm volatile("" : "+v"(v))
#define PINF(v) asm volatile("" : "+v"(v))

// Prep: Wt[t][j][c] = Wout[j][4t+c]  (per-step Wout column contiguous:
// uniform base bump 448B/step + constant lane offset).
__global__ void transpose_wout(const float* __restrict__ Wout, float* __restrict__ Wt) {
    int idx = blockIdx.x * 256 + threadIdx.x;     // 200*28*4 = 22400
    if (idx < T_STEPS * OUTD * 4) {
        int t = idx / (OUTD * 4);
        int r = idx - t * (OUTD * 4);
        int j = r >> 2, c = r & 3;
        Wt[idx] = Wout[j * 800 + 4 * t + c];
    }
}

// One LSTM layer step for one element, lane k owns unit k of its quad.
// in = 4-vec input (as two f2), h = own-layer hidden (two f2, quad-replicated),
// c = own cell. Updates h (re-broadcast via DPP) and c.
__device__ __forceinline__ void layer_step(const f2 (&wia)[4], const f2 (&wib)[4],
                                           const f2 (&wha)[4], const f2 (&whb)[4],
                                           const float (&bb)[4],
                                           f2 ina, f2 inb,
                                           f2& ha, f2& hb, float& c)
{
    float g[4];
#pragma unroll
    for (int gi = 0; gi < 4; ++gi) {
        f2 s = wia[gi] * ina;
        s += wib[gi] * inb;
        s += wha[gi] * ha;
        s += whb[gi] * hb;
        g[gi] = bb[gi] + s.x + s.y;
    }
    float ig = sigm(g[0]), fg = sigm(g[1]);
    float gg = tanh_fast(g[2]), og = sigm(g[3]);
    c = fg * c + ig * gg;
    float ho = og * tanh_fast(c);
    ha = f2{qb<0>(ho), qb<1>(ho)};
    hb = f2{qb<2>(ho), qb<3>(ho)};
}

// 4 lanes per batch-element PAIR: lane k owns hidden unit k of TWO elements
// (weights shared across the pair). 32768 elem / 2 * 4 lanes = 65536 threads
// = 1024 waves = exactly 1 wave/SIMD; amdgpu_waves_per_eu(1,1) gives the
// allocator the full 512-reg budget so the ~170-reg live set (weights + two
// recurrence states + wo/x prefetch) is genuinely register-resident (R2-R4:
// at 2 waves/SIMD the allocator capped ~88 VGPRs and reloaded weights every
// step). Latency hiding comes from in-wave ILP: two independent chains
// interleave through the trans/DPP/VMEM gaps.
__global__ __launch_bounds__(256)
__attribute__((amdgpu_waves_per_eu(1, 1)))
void lstm2_fused(const float* __restrict__ x,
                 const float* __restrict__ Wih0, const float* __restrict__ Whh0,
                 const float* __restrict__ bih0, const float* __restrict__ bhh0,
                 const float* __restrict__ Wih1, const float* __restrict__ Whh1,
                 const float* __restrict__ bih1, const float* __restrict__ bhh1,
                 const float* __restrict__ Wt,   const float* __restrict__ bout,
                 float* __restrict__ out, int batch)
{
    const int tid = blockIdx.x * 256 + threadIdx.x;
    const int quad = tid >> 2;     // element pair
    const int k = tid & 3;         // hidden unit owned by this lane
    const int e0 = quad * 2, e1 = e0 + 1;
    if (e1 >= batch) return;       // never taken (batch even)

    // ---- per-lane weights into registers (f2 pairs), shared by both elements ----
    f2 wi0a[4], wi0b[4], wh0a[4], wh0b[4];
    f2 wi1a[4], wi1b[4], wh1a[4], wh1b[4];
    float b0[4], b1[4];
#pragma unroll
    for (int gi = 0; gi < 4; ++gi) {
        const int row = gi * 4 + k;              // rows k,4+k,8+k,12+k
        float4 a = ((const float4*)Wih0)[row];
        float4 c = ((const float4*)Whh0)[row];
        float4 d = ((const float4*)Wih1)[row];
        float4 e = ((const float4*)Whh1)[row];
        wi0a[gi] = f2{a.x, a.y}; wi0b[gi] = f2{a.z, a.w};
        wh0a[gi] = f2{c.x, c.y}; wh0b[gi] = f2{c.z, c.w};
        wi1a[gi] = f2{d.x, d.y}; wi1b[gi] = f2{d.z, d.w};
        wh1a[gi] = f2{e.x, e.y}; wh1b[gi] = f2{e.z, e.w};
        b0[gi] = bih0[row] + bhh0[row];
        b1[gi] = bih1[row] + bhh1[row];
    }
#pragma unroll
    for (int gi = 0; gi < 4; ++gi) {
        PIN2(wi0a[gi]); PIN2(wi0b[gi]); PIN2(wh0a[gi]); PIN2(wh0b[gi]);
        PIN2(wi1a[gi]); PIN2(wi1b[gi]); PIN2(wh1a[gi]); PIN2(wh1b[gi]);
        PINF(b0[gi]);   PINF(b1[gi]);
    }

    f2 acc0[7], acc1[7];
#pragma unroll
    for (int jj = 0; jj < 7; ++jj) {
        float bj = bout[k * 7 + jj];
        acc0[jj] = f2{bj, 0.0f};
        acc1[jj] = f2{bj, 0.0f};
    }

    f2 h1a0 = f2{0,0}, h1b0 = f2{0,0}, h2a0 = f2{0,0}, h2b0 = f2{0,0};
    f2 h1a1 = f2{0,0}, h1b1 = f2{0,0}, h2a1 = f2{0,0}, h2b1 = f2{0,0};
    float c10 = 0.0f, c20 = 0.0f, c11 = 0.0f, c21 = 0.0f;

    // Uniform bases (SALU-advanced) + constant per-lane byte offsets.
    const char* xp  = (const char*)x;
    const unsigned xo0 = (unsigned)e0 * 3200u;        // e * 200*4*4B
    const unsigned xo1 = (unsigned)e1 * 3200u;
    const char* wtp = (const char*)Wt;                // + 448 each step
    const unsigned w_off = (unsigned)k * 112u;        // k*7 rows * 16B

    // Depth-2 x prefetch (1 wave/SIMD: no sibling wave to cover HBM misses).
    float4 xv0 = *(const float4*)(xp + xo0);
    float4 xv1 = *(const float4*)(xp + xo1);
    float4 xn0 = *(const float4*)(xp + xo0 + 16);
    float4 xn1 = *(const float4*)(xp + xo1 + 16);

    for (int t = 0; t < T_STEPS; ++t) {
        // ---- this step's Wout column (shared by both elements) ----
        float4 wo[7];
#pragma unroll
        for (int jj = 0; jj < 7; ++jj)
            wo[jj] = *(const float4*)(wtp + w_off + jj * 16);
        wtp += OUTD * 16;                              // uniform s_add

        int tn = t + 2; if (tn >= T_STEPS) tn = T_STEPS - 1;   // uniform
        float4 xf0 = *(const float4*)(xp + xo0 + (size_t)tn * 16);
        float4 xf1 = *(const float4*)(xp + xo1 + (size_t)tn * 16);

        // ---- layer 1, both elements (independent chains -> ILP) ----
        layer_step(wi0a, wi0b, wh0a, wh0b, b0,
                   f2{xv0.x, xv0.y}, f2{xv0.z, xv0.w}, h1a0, h1b0, c10);
        layer_step(wi0a, wi0b, wh0a, wh0b, b0,
                   f2{xv1.x, xv1.y}, f2{xv1.z, xv1.w}, h1a1, h1b1, c11);

        // ---- layer 2, both elements ----
        layer_step(wi1a, wi1b, wh1a, wh1b, b1, h1a0, h1b0, h2a0, h2b0, c20);
        layer_step(wi1a, wi1b, wh1a, wh1b, b1, h1a1, h1b1, h2a1, h2b1, c21);

        // ---- fused linear, both elements (wo shared) ----
#pragma unroll
        for (int jj = 0; jj < 7; ++jj) {
            f2 wa = f2{wo[jj].x, wo[jj].y};
            f2 wb = f2{wo[jj].z, wo[jj].w};
            acc0[jj] += wa * h2a0; acc0[jj] += wb * h2b0;
            acc1[jj] += wa * h2a1; acc1[jj] += wb * h2b1;
        }

        xv0 = xn0; xv1 = xn1;
        xn0 = xf0; xn1 = xf1;
    }

    float* op0 = out + (size_t)e0 * OUTD + k * 7;
    float* op1 = out + (size_t)e1 * OUTD + k * 7;
#pragma unroll
    for (int jj = 0; jj < 7; ++jj) {
        op0[jj] = acc0[jj].x + acc0[jj].y;
        op1[jj] = acc1[jj].x + acc1[jj].y;
    }
}

extern "C" void kernel_launch(void* const* d_in, const int* in_sizes, int n_in,
                              void* d_out, int out_size, void* d_ws, size_t ws_size,
                              hipStream_t stream) {
    const float* x    = (const float*)d_in[0];
    const float* Wih0 = (const float*)d_in[1];
    const float* Whh0 = (const float*)d_in[2];
    const float* bih0 = (const float*)d_in[3];
    const float* bhh0 = (const float*)d_in[4];
    const float* Wih1 = (const float*)d_in[5];
    const float* Whh1 = (const float*)d_in[6];
    const float* bih1 = (const float*)d_in[7];
    const float* bhh1 = (const float*)d_in[8];
    const float* Wout = (const float*)d_in[9];
    const float* bout = (const float*)d_in[10];
    float* out = (float*)d_out;
    float* Wt  = (float*)d_ws;      // 200*28*4 floats = 89.6 KB

    transpose_wout<<<(T_STEPS * OUTD * 4 + 255) / 256, 256, 0, stream>>>(Wout, Wt);

    const int batch = in_sizes[0] / (T_STEPS * 4);   // 32768
    const int threads = (batch / 2) * 4;             // 65536
    const int grid = threads / 256;                  // 256
    lstm2_fused<<<grid, 256, 0, stream>>>(
        x, Wih0, Whh0, bih0, bhh0, Wih1, Whh1, bih1, bhh1, Wt, bout, out, batch);
}